// Round 1
// baseline (1786.935 us; speedup 1.0000x reference)
//
#include <hip/hip_runtime.h>
#include <math.h>

// ---------------------------------------------------------------------------
// Problem: N=2048, M=2048, D=1024, EMB=64, HEADS=16
//   q   = ref_feat @ Wq_w.T + Wq_b            [N,D]
//   k   = sup_feat @ Wk_w.T + Wk_b            [M,D]
//   aff = (q @ k.T) / 32                      [N,M]
//   pos[h,n,m] = relu(sum_e Wg_w[h,e]*PE[e,n,m] + Wg_b[h])
//   out[n,m] = ( mean_h sigmoid(log(pos+1e-6)+aff) > 0.5 ) ? 1 : 0
// Identity used: sigmoid(log(w')+a) = w' / (w' + exp(-a)),  w' = relu(x)+1e-6
// All fp32 (binary threshold output => bf16 MFMA would flip boundary bits).
// ---------------------------------------------------------------------------

#define GN 2048
#define GM 2048
#define GD 1024
#define GEMB 64
#define GHEADS 16

// ------------------------- fp32 GEMM:  C = scale * (A @ B^T) + bias ---------
// A: [M_,K_] row-major, B: [N_,K_] row-major, C: [M_,N_]
// 128x128 block tile, 256 threads, 8x8 micro-tile, BK=16.
#define BM 128
#define BN 128
#define BK 16
#define LDP (BM + 4)   // padded LDS leading dim (floats)

__global__ __launch_bounds__(256) void gemm_nt(const float* __restrict__ A,
                                               const float* __restrict__ B,
                                               const float* __restrict__ bias,
                                               float* __restrict__ C,
                                               int N_, int K_, float scale) {
    __shared__ float As[BK][LDP];
    __shared__ float Bs[BK][LDP];

    const int t  = threadIdx.x;
    const int tx = t & 15;        // 0..15 -> col group
    const int ty = t >> 4;        // 0..15 -> row group
    const int row0 = blockIdx.y * BM;
    const int col0 = blockIdx.x * BN;

    float acc[8][8];
#pragma unroll
    for (int i = 0; i < 8; ++i)
#pragma unroll
        for (int j = 0; j < 8; ++j) acc[i][j] = 0.0f;

    for (int k0 = 0; k0 < K_; k0 += BK) {
        // stage A,B tiles: 128 rows x 16 k = 512 float4 slots each; 2/thread
#pragma unroll
        for (int i = 0; i < 2; ++i) {
            const int idx = t + i * 256;        // 0..511
            const int r   = idx >> 2;           // row within tile
            const int c4  = (idx & 3) << 2;     // k offset {0,4,8,12}
            float4 av = *(const float4*)&A[(size_t)(row0 + r) * K_ + k0 + c4];
            As[c4 + 0][r] = av.x;
            As[c4 + 1][r] = av.y;
            As[c4 + 2][r] = av.z;
            As[c4 + 3][r] = av.w;
            float4 bv = *(const float4*)&B[(size_t)(col0 + r) * K_ + k0 + c4];
            Bs[c4 + 0][r] = bv.x;
            Bs[c4 + 1][r] = bv.y;
            Bs[c4 + 2][r] = bv.z;
            Bs[c4 + 3][r] = bv.w;
        }
        __syncthreads();

#pragma unroll
        for (int kk = 0; kk < BK; ++kk) {
            float a[8], b[8];
            *(float4*)&a[0] = *(const float4*)&As[kk][ty * 8];
            *(float4*)&a[4] = *(const float4*)&As[kk][ty * 8 + 4];
            *(float4*)&b[0] = *(const float4*)&Bs[kk][tx * 8];
            *(float4*)&b[4] = *(const float4*)&Bs[kk][tx * 8 + 4];
#pragma unroll
            for (int i = 0; i < 8; ++i)
#pragma unroll
                for (int j = 0; j < 8; ++j) acc[i][j] = fmaf(a[i], b[j], acc[i][j]);
        }
        __syncthreads();
    }

    // epilogue
#pragma unroll
    for (int i = 0; i < 8; ++i) {
        const int r = row0 + ty * 8 + i;
#pragma unroll
        for (int j = 0; j < 8; j += 4) {
            const int c = col0 + tx * 8 + j;
            float4 v;
            v.x = acc[i][j + 0] * scale;
            v.y = acc[i][j + 1] * scale;
            v.z = acc[i][j + 2] * scale;
            v.w = acc[i][j + 3] * scale;
            if (bias) {
                v.x += bias[c + 0];
                v.y += bias[c + 1];
                v.z += bias[c + 2];
                v.w += bias[c + 3];
            }
            *(float4*)&C[(size_t)r * N_ + c] = v;
        }
    }
}

// ------------------------- main: stream PE, gate, sigmoid-mean threshold ----
// One thread handles 4 consecutive m. Block = 256 threads => 1024 columns.
// grid = (GM/1024, GN)
__global__ __launch_bounds__(256) void adj_main(const float* __restrict__ PE,
                                                const float* __restrict__ Wg_w,
                                                const float* __restrict__ Wg_b,
                                                const float* __restrict__ aff,
                                                float* __restrict__ out) {
    __shared__ float wgs[GHEADS * GEMB];   // 1024 floats
    __shared__ float wbs[GHEADS];

    const int t = threadIdx.x;
    // load gate weights into LDS (broadcast reads later => conflict-free)
    *(float4*)&wgs[t * 4] = *(const float4*)&Wg_w[t * 4];
    if (t < GHEADS) wbs[t] = Wg_b[t];
    __syncthreads();

    const int n  = blockIdx.y;
    const int m0 = blockIdx.x * 1024 + t * 4;
    const size_t nm = (size_t)n * GM + m0;
    const size_t chanStride = (size_t)GN * GM;

    float acc[GHEADS][4];
#pragma unroll
    for (int h = 0; h < GHEADS; ++h) {
        const float b = wbs[h];
        acc[h][0] = b; acc[h][1] = b; acc[h][2] = b; acc[h][3] = b;
    }

    const float* pe = PE + nm;
#pragma unroll 4
    for (int e = 0; e < GEMB; ++e) {
        const float4 p = *(const float4*)&pe[(size_t)e * chanStride];
#pragma unroll
        for (int h = 0; h < GHEADS; ++h) {
            const float w = wgs[h * GEMB + e];
            acc[h][0] = fmaf(w, p.x, acc[h][0]);
            acc[h][1] = fmaf(w, p.y, acc[h][1]);
            acc[h][2] = fmaf(w, p.z, acc[h][2]);
            acc[h][3] = fmaf(w, p.w, acc[h][3]);
        }
    }

    const float4 av = *(const float4*)&aff[nm];
    float E[4];
    E[0] = expf(-av.x);
    E[1] = expf(-av.y);
    E[2] = expf(-av.z);
    E[3] = expf(-av.w);

    float s[4] = {0.f, 0.f, 0.f, 0.f};
#pragma unroll
    for (int h = 0; h < GHEADS; ++h) {
#pragma unroll
        for (int j = 0; j < 4; ++j) {
            const float wp = fmaxf(acc[h][j], 0.0f) + 1e-6f;
            s[j] += wp * __builtin_amdgcn_rcpf(wp + E[j]);
        }
    }

    float4 o;
    o.x = (s[0] * 0.0625f > 0.5f) ? 1.0f : 0.0f;
    o.y = (s[1] * 0.0625f > 0.5f) ? 1.0f : 0.0f;
    o.z = (s[2] * 0.0625f > 0.5f) ? 1.0f : 0.0f;
    o.w = (s[3] * 0.0625f > 0.5f) ? 1.0f : 0.0f;
    *(float4*)&out[nm] = o;
}

// ---------------------------------------------------------------------------
extern "C" void kernel_launch(void* const* d_in, const int* in_sizes, int n_in,
                              void* d_out, int out_size, void* d_ws, size_t ws_size,
                              hipStream_t stream) {
    const float* ref_feat = (const float*)d_in[0];   // [2048,1024]
    const float* sup_feat = (const float*)d_in[1];   // [2048,1024]
    const float* pos_emb  = (const float*)d_in[2];   // [1,64,2048,2048]
    const float* Wg_w     = (const float*)d_in[3];   // [16,64]
    const float* Wg_b     = (const float*)d_in[4];   // [16]
    const float* Wq_w     = (const float*)d_in[5];   // [1024,1024]
    const float* Wq_b     = (const float*)d_in[6];   // [1024]
    const float* Wk_w     = (const float*)d_in[7];   // [1024,1024]
    const float* Wk_b     = (const float*)d_in[8];   // [1024]
    float* out = (float*)d_out;                      // [2048,2048]

    // workspace layout (floats): q[2048*1024] | k[2048*1024] | aff[2048*2048]
    float* q   = (float*)d_ws;
    float* k   = q + (size_t)GN * GD;
    float* aff = k + (size_t)GM * GD;

    // q = ref_feat @ Wq^T + Wq_b      (2048 x 1024, K=1024)
    gemm_nt<<<dim3(GD / BN, GN / BM), 256, 0, stream>>>(ref_feat, Wq_w, Wq_b, q,
                                                        GD, GD, 1.0f);
    // k = sup_feat @ Wk^T + Wk_b
    gemm_nt<<<dim3(GD / BN, GM / BM), 256, 0, stream>>>(sup_feat, Wk_w, Wk_b, k,
                                                        GD, GD, 1.0f);
    // aff = (q @ k^T) * (1/32)        (2048 x 2048, K=1024)
    gemm_nt<<<dim3(GM / BN, GN / BM), 256, 0, stream>>>(q, k, nullptr, aff,
                                                        GM, GD, 0.03125f);
    // fused gate + sigmoid-mean + threshold
    adj_main<<<dim3(GM / 1024, GN), 256, 0, stream>>>(pos_emb, Wg_w, Wg_b, aff, out);
}

// Round 2
// 1704.142 us; speedup vs baseline: 1.0486x; 1.0486x over previous
//
#include <hip/hip_runtime.h>
#include <math.h>

// ---------------------------------------------------------------------------
// Problem: N=2048, M=2048, D=1024, EMB=64, HEADS=16
//   q   = ref_feat @ Wq_w.T + Wq_b            [N,D]
//   k   = sup_feat @ Wk_w.T + Wk_b            [M,D]
//   aff = (q @ k.T) / 32                      [N,M]
//   pos[h,n,m] = relu(sum_e Wg_w[h,e]*PE[e,n,m] + Wg_b[h])
//   out[n,m] = ( mean_h sigmoid(log(pos+1e-6)+aff) > 0.5 ) ? 1 : 0
// Identity: sigmoid(log(w')+a) = w' / (w' + exp(-a)),  w' = relu(x)+1e-6
// All fp32 (binary threshold output => bf16 MFMA would flip boundary bits).
//
// R2 structure:
//   K1 gemm_qk   : q and k in ONE dispatch (grid.z=2 -> 256 blocks, full chip),
//                  register-prefetch double-buffered staging. Also writes
//                  transposed gate weights wT[e][h] to ws for scalar loads.
//   K2 fused_adj : per 128x128 tile: aff in registers -> exp(-aff/32) to LDS
//                  (overlaid on As/Bs), then stream PE slice + gate + sigmoid
//                  -> out. aff never hits HBM.
// ---------------------------------------------------------------------------

#define GN 2048
#define GM 2048
#define GD 1024
#define GEMB 64
#define GHEADS 16
#define CHANSTRIDE ((size_t)GN * GM)   // floats per PE channel

#define BM 128
#define BN 128
#define BK 16
#define LDP (BM + 4)   // padded LDS leading dim (floats)

// ---------------- K1: q,k GEMM (C = A @ B^T + bias), full chip --------------
__global__ __launch_bounds__(256) void gemm_qk(const float* __restrict__ ref,
                                               const float* __restrict__ sup,
                                               const float* __restrict__ Wq_w,
                                               const float* __restrict__ Wq_b,
                                               const float* __restrict__ Wk_w,
                                               const float* __restrict__ Wk_b,
                                               const float* __restrict__ Wg_w,
                                               float* __restrict__ q,
                                               float* __restrict__ k,
                                               float* __restrict__ wT) {
    __shared__ float As[BK][LDP];
    __shared__ float Bs[BK][LDP];

    const int z = blockIdx.z;
    const float* A    = z ? sup  : ref;
    const float* B    = z ? Wk_w : Wq_w;
    const float* bias = z ? Wk_b : Wq_b;
    float*       C    = z ? k    : q;

    const int t  = threadIdx.x;
    const int tx = t & 15;
    const int ty = t >> 4;
    const int row0 = blockIdx.y * BM;
    const int col0 = blockIdx.x * BN;

    // one block transposes the 16x64 gate weights into ws (wT[e*16+h])
    if (z == 0 && blockIdx.x == 0 && blockIdx.y == 0 && t < GEMB) {
#pragma unroll
        for (int h = 0; h < GHEADS; ++h) wT[t * GHEADS + h] = Wg_w[h * GEMB + t];
    }

    float acc[8][8];
#pragma unroll
    for (int i = 0; i < 8; ++i)
#pragma unroll
        for (int j = 0; j < 8; ++j) acc[i][j] = 0.0f;

    float4 pa[2], pb[2];
    // prologue: load tile k0=0
#pragma unroll
    for (int i = 0; i < 2; ++i) {
        const int idx = t + i * 256;
        const int r   = idx >> 2;
        const int c4  = (idx & 3) << 2;
        pa[i] = *(const float4*)&A[(size_t)(row0 + r) * GD + c4];
        pb[i] = *(const float4*)&B[(size_t)(col0 + r) * GD + c4];
    }
#pragma unroll
    for (int i = 0; i < 2; ++i) {
        const int idx = t + i * 256;
        const int r   = idx >> 2;
        const int c4  = (idx & 3) << 2;
        As[c4 + 0][r] = pa[i].x; As[c4 + 1][r] = pa[i].y;
        As[c4 + 2][r] = pa[i].z; As[c4 + 3][r] = pa[i].w;
        Bs[c4 + 0][r] = pb[i].x; Bs[c4 + 1][r] = pb[i].y;
        Bs[c4 + 2][r] = pb[i].z; Bs[c4 + 3][r] = pb[i].w;
    }
    __syncthreads();

    for (int k0 = 0; k0 < GD; k0 += BK) {
        const bool more = (k0 + BK) < GD;
        if (more) {
#pragma unroll
            for (int i = 0; i < 2; ++i) {
                const int idx = t + i * 256;
                const int r   = idx >> 2;
                const int c4  = (idx & 3) << 2;
                pa[i] = *(const float4*)&A[(size_t)(row0 + r) * GD + k0 + BK + c4];
                pb[i] = *(const float4*)&B[(size_t)(col0 + r) * GD + k0 + BK + c4];
            }
        }
#pragma unroll
        for (int kk = 0; kk < BK; ++kk) {
            float a[8], b[8];
            *(float4*)&a[0] = *(const float4*)&As[kk][ty * 8];
            *(float4*)&a[4] = *(const float4*)&As[kk][ty * 8 + 4];
            *(float4*)&b[0] = *(const float4*)&Bs[kk][tx * 8];
            *(float4*)&b[4] = *(const float4*)&Bs[kk][tx * 8 + 4];
#pragma unroll
            for (int i = 0; i < 8; ++i)
#pragma unroll
                for (int j = 0; j < 8; ++j) acc[i][j] = fmaf(a[i], b[j], acc[i][j]);
        }
        __syncthreads();
        if (more) {
#pragma unroll
            for (int i = 0; i < 2; ++i) {
                const int idx = t + i * 256;
                const int r   = idx >> 2;
                const int c4  = (idx & 3) << 2;
                As[c4 + 0][r] = pa[i].x; As[c4 + 1][r] = pa[i].y;
                As[c4 + 2][r] = pa[i].z; As[c4 + 3][r] = pa[i].w;
                Bs[c4 + 0][r] = pb[i].x; Bs[c4 + 1][r] = pb[i].y;
                Bs[c4 + 2][r] = pb[i].z; Bs[c4 + 3][r] = pb[i].w;
            }
        }
        __syncthreads();
    }

#pragma unroll
    for (int i = 0; i < 8; ++i) {
        const int r = row0 + ty * 8 + i;
#pragma unroll
        for (int j = 0; j < 8; j += 4) {
            const int c = col0 + tx * 8 + j;
            float4 v;
            v.x = acc[i][j + 0] + bias[c + 0];
            v.y = acc[i][j + 1] + bias[c + 1];
            v.z = acc[i][j + 2] + bias[c + 2];
            v.w = acc[i][j + 3] + bias[c + 3];
            *(float4*)&C[(size_t)r * GD + c] = v;
        }
    }
}

// ---------------- K2: aff tile (regs) -> exp to LDS -> PE stream -> out -----
__global__ __launch_bounds__(256) void fused_adj(const float* __restrict__ q,
                                                 const float* __restrict__ k,
                                                 const float* __restrict__ PE,
                                                 const float* __restrict__ wT,
                                                 const float* __restrict__ Wg_b,
                                                 float* __restrict__ out) {
    __shared__ float lds[BM * BN];                 // 64 KB union
    float(*As)[LDP] = (float(*)[LDP])lds;          // phase-1 view
    float(*Bs)[LDP] = (float(*)[LDP])(lds + BK * LDP);
    float* El = lds;                               // phase-2 view: exp(-aff/32)

    const int t  = threadIdx.x;
    const int tx = t & 15;
    const int ty = t >> 4;
    const int n0 = blockIdx.y * BM;
    const int m0 = blockIdx.x * BN;

    // ---------------- phase 1: aff = q @ k^T / 32 ---------------------------
    float acc[8][8];
#pragma unroll
    for (int i = 0; i < 8; ++i)
#pragma unroll
        for (int j = 0; j < 8; ++j) acc[i][j] = 0.0f;

    float4 pa[2], pb[2];
#pragma unroll
    for (int i = 0; i < 2; ++i) {
        const int idx = t + i * 256;
        const int r   = idx >> 2;
        const int c4  = (idx & 3) << 2;
        pa[i] = *(const float4*)&q[(size_t)(n0 + r) * GD + c4];
        pb[i] = *(const float4*)&k[(size_t)(m0 + r) * GD + c4];
    }
#pragma unroll
    for (int i = 0; i < 2; ++i) {
        const int idx = t + i * 256;
        const int r   = idx >> 2;
        const int c4  = (idx & 3) << 2;
        As[c4 + 0][r] = pa[i].x; As[c4 + 1][r] = pa[i].y;
        As[c4 + 2][r] = pa[i].z; As[c4 + 3][r] = pa[i].w;
        Bs[c4 + 0][r] = pb[i].x; Bs[c4 + 1][r] = pb[i].y;
        Bs[c4 + 2][r] = pb[i].z; Bs[c4 + 3][r] = pb[i].w;
    }
    __syncthreads();

    for (int k0 = 0; k0 < GD; k0 += BK) {
        const bool more = (k0 + BK) < GD;
        if (more) {
#pragma unroll
            for (int i = 0; i < 2; ++i) {
                const int idx = t + i * 256;
                const int r   = idx >> 2;
                const int c4  = (idx & 3) << 2;
                pa[i] = *(const float4*)&q[(size_t)(n0 + r) * GD + k0 + BK + c4];
                pb[i] = *(const float4*)&k[(size_t)(m0 + r) * GD + k0 + BK + c4];
            }
        }
#pragma unroll
        for (int kk = 0; kk < BK; ++kk) {
            float a[8], b[8];
            *(float4*)&a[0] = *(const float4*)&As[kk][ty * 8];
            *(float4*)&a[4] = *(const float4*)&As[kk][ty * 8 + 4];
            *(float4*)&b[0] = *(const float4*)&Bs[kk][tx * 8];
            *(float4*)&b[4] = *(const float4*)&Bs[kk][tx * 8 + 4];
#pragma unroll
            for (int i = 0; i < 8; ++i)
#pragma unroll
                for (int j = 0; j < 8; ++j) acc[i][j] = fmaf(a[i], b[j], acc[i][j]);
        }
        __syncthreads();
        if (more) {
#pragma unroll
            for (int i = 0; i < 2; ++i) {
                const int idx = t + i * 256;
                const int r   = idx >> 2;
                const int c4  = (idx & 3) << 2;
                As[c4 + 0][r] = pa[i].x; As[c4 + 1][r] = pa[i].y;
                As[c4 + 2][r] = pa[i].z; As[c4 + 3][r] = pa[i].w;
                Bs[c4 + 0][r] = pb[i].x; Bs[c4 + 1][r] = pb[i].y;
                Bs[c4 + 2][r] = pb[i].z; Bs[c4 + 3][r] = pb[i].w;
            }
        }
        __syncthreads();
    }

    // E = exp(-aff/32) into LDS (overlaying As/Bs — all reads are done)
#pragma unroll
    for (int i = 0; i < 8; ++i) {
        const int r = ty * 8 + i;
#pragma unroll
        for (int j = 0; j < 8; j += 4) {
            const int c = tx * 8 + j;
            float4 ev;
            ev.x = expf(-acc[i][j + 0] * 0.03125f);
            ev.y = expf(-acc[i][j + 1] * 0.03125f);
            ev.z = expf(-acc[i][j + 2] * 0.03125f);
            ev.w = expf(-acc[i][j + 3] * 0.03125f);
            *(float4*)&El[r * BN + c] = ev;
        }
    }
    __syncthreads();

    // ---------------- phase 2: stream PE, gate, sigmoid-mean, threshold ----
    // 16 chunks; chunk covers 4 consecutive m of one row. Half-wave reads
    // 512 B contiguous per channel -> coalesced.
    for (int c = 0; c < 16; ++c) {
        const int chunk = c * 256 + t;
        const int r     = chunk >> 5;          // local row 0..127
        const int c4    = (chunk & 31) << 2;   // local col 0..124
        const float* peBase = PE + (size_t)(n0 + r) * GM + m0 + c4;

        float4 g[GHEADS];
#pragma unroll
        for (int h = 0; h < GHEADS; ++h) {
            const float b = Wg_b[h];           // uniform -> s_load
            g[h].x = b; g[h].y = b; g[h].z = b; g[h].w = b;
        }
#pragma unroll 4
        for (int e = 0; e < GEMB; ++e) {
            const float4 p = *(const float4*)(peBase + (size_t)e * CHANSTRIDE);
#pragma unroll
            for (int h = 0; h < GHEADS; ++h) {
                const float w = wT[e * GHEADS + h];   // uniform -> s_load
                g[h].x = fmaf(w, p.x, g[h].x);
                g[h].y = fmaf(w, p.y, g[h].y);
                g[h].z = fmaf(w, p.z, g[h].z);
                g[h].w = fmaf(w, p.w, g[h].w);
            }
        }

        const float4 Ev = *(const float4*)&El[r * BN + c4];
        float s0 = 0.f, s1 = 0.f, s2 = 0.f, s3 = 0.f;
#pragma unroll
        for (int h = 0; h < GHEADS; ++h) {
            float wp;
            wp = fmaxf(g[h].x, 0.0f) + 1e-6f; s0 += wp * __builtin_amdgcn_rcpf(wp + Ev.x);
            wp = fmaxf(g[h].y, 0.0f) + 1e-6f; s1 += wp * __builtin_amdgcn_rcpf(wp + Ev.y);
            wp = fmaxf(g[h].z, 0.0f) + 1e-6f; s2 += wp * __builtin_amdgcn_rcpf(wp + Ev.z);
            wp = fmaxf(g[h].w, 0.0f) + 1e-6f; s3 += wp * __builtin_amdgcn_rcpf(wp + Ev.w);
        }
        float4 o;
        o.x = (s0 * 0.0625f > 0.5f) ? 1.0f : 0.0f;
        o.y = (s1 * 0.0625f > 0.5f) ? 1.0f : 0.0f;
        o.z = (s2 * 0.0625f > 0.5f) ? 1.0f : 0.0f;
        o.w = (s3 * 0.0625f > 0.5f) ? 1.0f : 0.0f;
        *(float4*)&out[(size_t)(n0 + r) * GM + m0 + c4] = o;
    }
}

// ---------------------------------------------------------------------------
extern "C" void kernel_launch(void* const* d_in, const int* in_sizes, int n_in,
                              void* d_out, int out_size, void* d_ws, size_t ws_size,
                              hipStream_t stream) {
    const float* ref_feat = (const float*)d_in[0];   // [2048,1024]
    const float* sup_feat = (const float*)d_in[1];   // [2048,1024]
    const float* pos_emb  = (const float*)d_in[2];   // [1,64,2048,2048]
    const float* Wg_w     = (const float*)d_in[3];   // [16,64]
    const float* Wg_b     = (const float*)d_in[4];   // [16]
    const float* Wq_w     = (const float*)d_in[5];   // [1024,1024]
    const float* Wq_b     = (const float*)d_in[6];   // [1024]
    const float* Wk_w     = (const float*)d_in[7];   // [1024,1024]
    const float* Wk_b     = (const float*)d_in[8];   // [1024]
    float* out = (float*)d_out;                      // [2048,2048]

    // ws layout (floats): q[2048*1024] | k[2048*1024] | wT[64*16]
    float* q  = (float*)d_ws;
    float* k  = q + (size_t)GN * GD;
    float* wT = k + (size_t)GM * GD;

    gemm_qk<<<dim3(GD / BN, GN / BM, 2), 256, 0, stream>>>(
        ref_feat, sup_feat, Wq_w, Wq_b, Wk_w, Wk_b, Wg_w, q, k, wT);

    fused_adj<<<dim3(GM / BN, GN / BM), 256, 0, stream>>>(
        q, k, pos_emb, wT, Wg_b, out);
}